// Round 1
// baseline (167.952 us; speedup 1.0000x reference)
//
#include <hip/hip_runtime.h>

#define IMG_W 1024
#define IMG_H 1024

__global__ __launch_bounds__(256) void dir_rhs_kernel(
    const float* __restrict__ u,
    const float* __restrict__ f,
    const float* __restrict__ wt,
    float* __restrict__ out)
{
    const int row = blockIdx.x;            // b*1024 + i
    const int b   = row >> 10;
    const int i   = row & (IMG_H - 1);
    const int tid = threadIdx.x;           // 0..255
    const int j0  = tid << 2;              // 4 columns per thread
    const size_t img = (size_t)b << 20;    // 1024*1024 elems per image

    float4* out4 = (float4*)(out + img + (size_t)i * IMG_W + j0);

    // Boundary rows: pure Dirichlet value (0)
    if (i == 0 || i == IMG_H - 1) {
        *out4 = make_float4(0.f, 0.f, 0.f, 0.f);
        return;
    }

    // Weights (broadcast loads, L1-cached)
    const float w00 = wt[0], w01 = wt[1], w02 = wt[2];
    const float w10 = wt[3], w11 = wt[4], w12 = wt[5];
    const float w20 = wt[6], w21 = wt[7], w22 = wt[8];
    const float cof = (float)(-(1.0 / 1023.0) * (1.0 / 1023.0) / 4.0);

    const float* urow = u + img + (size_t)i * IMG_W;

    float vm[6], vc[6], vp[6];

    const bool left_edge  = (j0 == 0);
    const bool right_edge = (j0 + 4 >= IMG_W);   // thread covering col 1023

    // ---- center row i (always interior here: 1 <= i <= 1022) ----
    {
        float4 c = *(const float4*)(urow + j0);
        vc[1] = c.x; vc[2] = c.y; vc[3] = c.z; vc[4] = c.w;
        vc[0] = left_edge  ? 0.f : urow[j0 - 1];
        vc[5] = right_edge ? 0.f : urow[j0 + 4];
        if (left_edge)  vc[1] = 0.f;   // col 0 is boundary in v
        if (right_edge) vc[4] = 0.f;   // col 1023 is boundary in v
    }
    // ---- north row i-1 ----
    if (i == 1) {
        #pragma unroll
        for (int k = 0; k < 6; k++) vm[k] = 0.f;   // row 0 is boundary in v
    } else {
        const float* r = urow - IMG_W;
        float4 c = *(const float4*)(r + j0);
        vm[1] = c.x; vm[2] = c.y; vm[3] = c.z; vm[4] = c.w;
        vm[0] = left_edge  ? 0.f : r[j0 - 1];
        vm[5] = right_edge ? 0.f : r[j0 + 4];
        if (left_edge)  vm[1] = 0.f;
        if (right_edge) vm[4] = 0.f;
    }
    // ---- south row i+1 ----
    if (i == IMG_H - 2) {
        #pragma unroll
        for (int k = 0; k < 6; k++) vp[k] = 0.f;   // row 1023 is boundary in v
    } else {
        const float* r = urow + IMG_W;
        float4 c = *(const float4*)(r + j0);
        vp[1] = c.x; vp[2] = c.y; vp[3] = c.z; vp[4] = c.w;
        vp[0] = left_edge  ? 0.f : r[j0 - 1];
        vp[5] = right_edge ? 0.f : r[j0 + 4];
        if (left_edge)  vp[1] = 0.f;
        if (right_edge) vp[4] = 0.f;
    }

    // ---- source term ----
    float4 f4 = *(const float4*)(f + img + (size_t)i * IMG_W + j0);
    float ff[4] = {f4.x, f4.y, f4.z, f4.w};

    float res[4];
    #pragma unroll
    for (int e = 0; e < 4; e++) {
        float acc = cof * ff[e];
        acc += w00 * vm[e] + w01 * vm[e + 1] + w02 * vm[e + 2];
        acc += w10 * vc[e] + w11 * vc[e + 1] + w12 * vc[e + 2];
        acc += w20 * vp[e] + w21 * vp[e + 1] + w22 * vp[e + 2];
        res[e] = acc;
    }
    // Boundary columns stay at the Dirichlet value
    if (left_edge)  res[0] = 0.f;
    if (right_edge) res[3] = 0.f;

    *out4 = make_float4(res[0], res[1], res[2], res[3]);
}

extern "C" void kernel_launch(void* const* d_in, const int* in_sizes, int n_in,
                              void* d_out, int out_size, void* d_ws, size_t ws_size,
                              hipStream_t stream) {
    const float* u  = (const float*)d_in[0];
    const float* f  = (const float*)d_in[1];
    const float* wt = (const float*)d_in[2];
    float* out = (float*)d_out;

    const int B = 16;
    dim3 grid(B * IMG_H);   // one block per (batch, row)
    dim3 block(256);        // 256 threads * 4 cols = 1024-wide row
    dir_rhs_kernel<<<grid, block, 0, stream>>>(u, f, wt, out);
}